// Round 10
// baseline (1328.509 us; speedup 1.0000x reference)
//
#include <hip/hip_runtime.h>
#include <hip/hip_fp16.h>
#include <cstdint>
#include <cstddef>

#define N_NODES_C  100000
#define N_EDGES_C  1600000
#define N_GRAPHS_C 256
#define HID_C      128
// 1/sqrt(1+1e-5)
#define BN_SCALE_C 0.9999950000374997f

#define SCAN_B 1024
#define SCAN_NB ((N_NODES_C + SCAN_B - 1) / SCAN_B)   // 98

// agg grid: 2048 blocks x 4 waves = 8192 waves, grid-stride over nodes
#define AGG_BLOCKS 2048
#define AGG_WAVES  (AGG_BLOCKS * 4)

typedef _Float16 h2 __attribute__((ext_vector_type(2)));
typedef _Float16 h4 __attribute__((ext_vector_type(4)));
typedef _Float16 h8 __attribute__((ext_vector_type(8)));
typedef float    f4 __attribute__((ext_vector_type(4)));

struct __align__(16) H8  { __half2 v[4]; };  // preamble convert

// ---------------------------------------------------------------------------
// CSR build: histogram of dst, inclusive scan, scatter edge ids.
// ---------------------------------------------------------------------------
__global__ __launch_bounds__(256) void hist_kernel(
    const int* __restrict__ dst, int* __restrict__ counts, int n_edges)
{
    int e = blockIdx.x * 256 + threadIdx.x;
    if (e < n_edges) atomicAdd(&counts[dst[e]], 1);
}

__global__ __launch_bounds__(SCAN_B) void scan1_kernel(
    const int* __restrict__ counts, int* __restrict__ incl,
    int* __restrict__ blocksums, int n)
{
    __shared__ int sdata[SCAN_B];
    const int lid = threadIdx.x;
    const int i = blockIdx.x * SCAN_B + lid;
    sdata[lid] = (i < n) ? counts[i] : 0;
    __syncthreads();
#pragma unroll
    for (int off = 1; off < SCAN_B; off <<= 1) {
        int t = (lid >= off) ? sdata[lid - off] : 0;
        __syncthreads();
        sdata[lid] += t;
        __syncthreads();
    }
    if (i < n) incl[i] = sdata[lid];
    if (lid == SCAN_B - 1) blocksums[blockIdx.x] = sdata[lid];
}

__global__ void scan2_kernel(const int* __restrict__ blocksums,
                             int* __restrict__ blockoffs, int nb)
{
    if (threadIdx.x == 0 && blockIdx.x == 0) {
        int off = 0;
        for (int b = 0; b < nb; ++b) { blockoffs[b] = off; off += blocksums[b]; }
    }
}

__global__ __launch_bounds__(SCAN_B) void scan3_kernel(
    int* __restrict__ incl, const int* __restrict__ blockoffs, int n)
{
    const int i = blockIdx.x * SCAN_B + threadIdx.x;
    if (i < n) incl[i] += blockoffs[blockIdx.x];
}

__global__ __launch_bounds__(256) void initrows_kernel(
    const int* __restrict__ incl, const int* __restrict__ counts,
    int* __restrict__ rowstart, int* __restrict__ cursor, int n)
{
    const int i = blockIdx.x * 256 + threadIdx.x;
    if (i < n) {
        const int rs = incl[i] - counts[i];
        rowstart[i] = rs;
        cursor[i]   = rs;
    }
}

// Fused scatter + edge_attr permute/convert: thread e reads its OWN
// edge_attr row (coalesced), converts to f16, writes 32B row to CSR slot.
__global__ __launch_bounds__(256) void scatter_ea_kernel(
    const int* __restrict__ src, const int* __restrict__ dst,
    int* __restrict__ cursor, int* __restrict__ perm_src,
    const float* __restrict__ edge_attr, __half* __restrict__ ea_f16,
    int n_edges)
{
    const int e = blockIdx.x * 256 + threadIdx.x;
    if (e >= n_edges) return;

    const float4* p = (const float4*)(edge_attr + (size_t)e * 16);
    const float4 q0 = p[0], q1 = p[1], q2 = p[2], q3 = p[3];

    const int pos = atomicAdd(&cursor[dst[e]], 1);
    perm_src[pos] = src[e];

    H8 a, b;
    a.v[0] = __floats2half2_rn(q0.x, q0.y);
    a.v[1] = __floats2half2_rn(q0.z, q0.w);
    a.v[2] = __floats2half2_rn(q1.x, q1.y);
    a.v[3] = __floats2half2_rn(q1.z, q1.w);
    b.v[0] = __floats2half2_rn(q2.x, q2.y);
    b.v[1] = __floats2half2_rn(q2.z, q2.w);
    b.v[2] = __floats2half2_rn(q3.x, q3.y);
    b.v[3] = __floats2half2_rn(q3.z, q3.w);
    H8* o = (H8*)(ea_f16 + (size_t)pos * 16);
    o[0] = a;
    o[1] = b;
}

// Cast fp32 array -> f16 (vectorized by 4).
__global__ __launch_bounds__(256) void cast_f16_kernel(
    const float* __restrict__ in, _Float16* __restrict__ out, int n4)
{
    const int i = blockIdx.x * 256 + threadIdx.x;
    if (i >= n4) return;
    const float4 v = ((const float4*)in)[i];
    h4 o; o[0] = (_Float16)v.x; o[1] = (_Float16)v.y;
    o[2] = (_Float16)v.z; o[3] = (_Float16)v.w;
    *(h4*)(out + (size_t)i * 4) = o;
}

// Transpose + cast weights: wt[n][k] = (f16) w[k][n].  (tiny, one-time)
__global__ __launch_bounds__(256) void transpose_w_kernel(
    const float* __restrict__ w, _Float16* __restrict__ wt, int K, int N)
{
    const int i = blockIdx.x * 256 + threadIdx.x;
    if (i >= K * N) return;
    const int n = i / K;
    const int k = i - n * K;
    wt[(size_t)n * K + k] = (_Float16)w[(size_t)k * N + n];
}

// ---------------------------------------------------------------------------
// CSR aggregate v2: MFMA edge MLP (moves the 16->DIN matmul off the VALU).
// One WAVE per node (grid-stride). Per 16-edge CSR tile:
//   A = ea[16 edges][16 dims], K zero-padded to 32 so we reuse the verified
//   mfma_f32_16x16x32_f16 layout: A[m=ln][k=quad*8+j] (quads 2,3 = zero);
//   B[k][n]: bfrag[b][j] = ew[quad*8+j][b*16+ln] (quads 2,3 = zero);
//   C-init = eb broadcast; C: col(f)=b*16+ln, row(edge)=quad*4+r.
// Epilogue per block: t = relu(msg + h16[src_r][f]); mask rows >= deg;
// lane-local sum over its 4 edges; butterfly shfl_xor(16,32) over quads;
// residual fused into the f16 x16 write.
// ---------------------------------------------------------------------------
template<int DIN>
__global__ __launch_bounds__(256) void gine_agg_mfma_kernel(
    const _Float16* __restrict__ hin, const _Float16* __restrict__ ea16,
    const int* __restrict__ perm_src,
    const int* __restrict__ rowstart, const int* __restrict__ rowend,
    const float* __restrict__ ew, const float* __restrict__ eb,
    _Float16* __restrict__ x16, int n_nodes)
{
    constexpr int NB  = DIN / 16;   // feature blocks (8 for 128, 4 for 64)
    constexpr int NB4 = NB / 4;     // blocks written per quad (2 / 1)

    const int lane = threadIdx.x & 63;
    const int wid  = blockIdx.x * 4 + (threadIdx.x >> 6);
    const int ln   = lane & 15;
    const int quad = lane >> 4;

    // ---- one-time B-fragments + bias (amortized over ~12 nodes/wave) ----
    h8 bfrag[NB];
    float ebf[NB];
#pragma unroll
    for (int b = 0; b < NB; ++b) {
        const int f = b * 16 + ln;
        h8 t = {};
        if (quad < 2) {
#pragma unroll
            for (int j = 0; j < 8; ++j)
                t[j] = (_Float16)ew[(size_t)(quad * 8 + j) * DIN + f];
        }
        bfrag[b] = t;
        ebf[b] = eb[f];
    }
    const h8 zero8 = {};

    for (int v = wid; v < n_nodes; v += AGG_WAVES) {
        const int s0 = rowstart[v];
        const int s1 = rowend[v];
        const int deg = s1 - s0;

        float acc[NB];
#pragma unroll
        for (int b = 0; b < NB; ++b) acc[b] = 0.f;

        for (int t0 = 0; t0 < deg; t0 += 16) {
            // A-frag: edge row = ln, dims quad*8..+7 (quads 0,1 only)
            h8 af = zero8;
            if (quad < 2) {
                int eA = s0 + t0 + ln;
                if (eA >= s1) eA = s1 - 1;
                af = *(const h8*)(ea16 + (size_t)eA * 16 + quad * 8);
            }
            // src ids for my 4 C-rows (edges quad*4+r), clamped
            int srcs[4];
#pragma unroll
            for (int r = 0; r < 4; ++r) {
                int er = s0 + t0 + quad * 4 + r;
                if (er >= s1) er = s1 - 1;
                srcs[r] = perm_src[er];
            }

#pragma unroll
            for (int b = 0; b < NB; ++b) {
                f4 c = {ebf[b], ebf[b], ebf[b], ebf[b]};
                c = __builtin_amdgcn_mfma_f32_16x16x32_f16(af, bfrag[b], c, 0, 0, 0);
                const int f = b * 16 + ln;
                float s = 0.f;
#pragma unroll
                for (int r = 0; r < 4; ++r) {
                    const float hv = (float)hin[(size_t)srcs[r] * DIN + f];
                    const float t = fmaxf(c[r] + hv, 0.f);
                    s += ((t0 + quad * 4 + r) < deg) ? t : 0.f;
                }
                acc[b] += s;
            }
        }

        // butterfly across quads: every lane gets the full sum for (b, ln)
#pragma unroll
        for (int b = 0; b < NB; ++b) {
            acc[b] += __shfl_xor(acc[b], 16);
            acc[b] += __shfl_xor(acc[b], 32);
        }

        // residual + f16 store: quad q writes blocks q*NB4 .. q*NB4+NB4-1
#pragma unroll
        for (int bb = 0; bb < NB4; ++bb) {
            const int b = quad * NB4 + bb;
            const int f = b * 16 + ln;
            const float hv = (float)hin[(size_t)v * DIN + f];
            x16[(size_t)v * DIN + f] = (_Float16)(acc[b] + hv);
        }
    }
}

// ---------------------------------------------------------------------------
// Node MLP: 1 wave per block, 1 16-node tile (round-9 verified structure).
// A-fragments for mm1 read DIRECTLY from global x16 (f16); s_t LDS only for
// the mm1->mm2 transpose. Always writes f16 h (pool reads f16).
// ---------------------------------------------------------------------------
template<int DIN>
__global__ __launch_bounds__(64) void node_mfma_kernel(
    const _Float16* __restrict__ x16,
    const _Float16* __restrict__ w1t, const float* __restrict__ b1,
    const float* __restrict__ gm, const float* __restrict__ bt,
    const _Float16* __restrict__ w2t, const float* __restrict__ b2,
    _Float16* __restrict__ h16out, int n_tiles)
{
    constexpr int STP = HID_C + 8;
    __shared__ _Float16 s_t[16][STP];

    const int lane = threadIdx.x;
    const int tile = blockIdx.x;
    const int node0 = tile * 16;
    const int ln   = lane & 15;
    const int quad = lane >> 4;

    constexpr int NKS = DIN / 32;
    h8 af[NKS];
#pragma unroll
    for (int ks = 0; ks < NKS; ++ks)
        af[ks] = *(const h8*)(x16 + (size_t)(node0 + ln) * DIN + ks * 32 + quad * 8);

    // ---- mm1 + BN + relu -> s_t (f16) ----
#pragma unroll
    for (int nt = 0; nt < 8; ++nt) {
        const int col = nt * 16 + ln;
        const float bv = b1[col];
        f4 acc = {bv, bv, bv, bv};
#pragma unroll
        for (int ks = 0; ks < NKS; ++ks) {
            const h8 bf = *(const h8*)(w1t + (size_t)col * DIN + ks * 32 + quad * 8);
            acc = __builtin_amdgcn_mfma_f32_16x16x32_f16(af[ks], bf, acc, 0, 0, 0);
        }
        const float gv = gm[col], btv = bt[col];
#pragma unroll
        for (int r = 0; r < 4; ++r) {
            const float t = fmaxf(fmaf(acc[r] * BN_SCALE_C, gv, btv), 0.f);
            s_t[quad * 4 + r][col] = (_Float16)t;
        }
    }
    __syncthreads();

    h8 af2[4];
#pragma unroll
    for (int ks = 0; ks < 4; ++ks)
        af2[ks] = *(const h8*)&s_t[ln][ks * 32 + quad * 8];

    // ---- mm2 + relu -> h16 ----
#pragma unroll
    for (int nt = 0; nt < 8; ++nt) {
        const int col = nt * 16 + ln;
        const float bv = b2[col];
        f4 acc = {bv, bv, bv, bv};
#pragma unroll
        for (int ks = 0; ks < 4; ++ks) {
            const h8 bf = *(const h8*)(w2t + (size_t)col * HID_C + ks * 32 + quad * 8);
            acc = __builtin_amdgcn_mfma_f32_16x16x32_f16(af2[ks], bf, acc, 0, 0, 0);
        }
#pragma unroll
        for (int r = 0; r < 4; ++r) {
            const int node = node0 + quad * 4 + r;
            h16out[(size_t)node * HID_C + col] = (_Float16)fmaxf(acc[r], 0.f);
        }
    }
}

// ---------------------------------------------------------------------------
// Pool + output MLP; reads the final f16 h.
// ---------------------------------------------------------------------------
__global__ __launch_bounds__(256) void pool_kernel(
    const _Float16* __restrict__ hfin, const int* __restrict__ batch,
    const float* __restrict__ w1, const float* __restrict__ b1,
    const float* __restrict__ w2, const float* __restrict__ b2,
    float* __restrict__ out, int n_nodes)
{
    const int gid = blockIdx.x;

    int lo = 0, hi = n_nodes;
    while (lo < hi) { int mid = (lo + hi) >> 1; if (batch[mid] < gid) lo = mid + 1; else hi = mid; }
    const int start = lo;
    hi = n_nodes;
    while (lo < hi) { int mid = (lo + hi) >> 1; if (batch[mid] < gid + 1) lo = mid + 1; else hi = mid; }
    const int end = lo;

    const int f = threadIdx.x & (HID_C - 1);
    const int half = threadIdx.x >> 7;

    float sum = 0.f;
    for (int n = start + half; n < end; n += 2)
        sum += (float)hfin[(size_t)n * HID_C + f];

    __shared__ float s_sum[2][HID_C];
    __shared__ float s_p[HID_C];
    __shared__ float s_t[HID_C];
    s_sum[half][f] = sum;
    __syncthreads();

    if (threadIdx.x < HID_C) {
        const float cnt = (float)(end - start);
        s_p[f] = (s_sum[0][f] + s_sum[1][f]) / fmaxf(cnt, 1.f);
    }
    __syncthreads();

    if (threadIdx.x < HID_C) {
        float acc = b1[f];
        for (int k = 0; k < HID_C; ++k) acc = fmaf(s_p[k], w1[k * HID_C + f], acc);
        s_t[f] = fmaxf(acc, 0.f);
    }
    __syncthreads();

    if (threadIdx.x < HID_C) {
        float acc = b2[f];
        for (int k = 0; k < HID_C; ++k) acc = fmaf(s_t[k], w2[k * HID_C + f], acc);
        out[(size_t)gid * HID_C + f] = acc;
    }
}

// ---------------------------------------------------------------------------
extern "C" void kernel_launch(void* const* d_in, const int* in_sizes, int n_in,
                              void* d_out, int out_size, void* d_ws, size_t ws_size,
                              hipStream_t stream)
{
    const float* x         = (const float*)d_in[0];
    const float* edge_attr = (const float*)d_in[1];
    const int*   edge_index= (const int*)  d_in[2];
    const int*   batch     = (const int*)  d_in[3];
    const int*   src = edge_index;
    const int*   dst = edge_index + N_EDGES_C;

    const float* el_w[3] = {(const float*)d_in[4],  (const float*)d_in[12], (const float*)d_in[20]};
    const float* el_b[3] = {(const float*)d_in[5],  (const float*)d_in[13], (const float*)d_in[21]};
    const float* c_w1[3] = {(const float*)d_in[6],  (const float*)d_in[14], (const float*)d_in[22]};
    const float* c_b1[3] = {(const float*)d_in[7],  (const float*)d_in[15], (const float*)d_in[23]};
    const float* c_g [3] = {(const float*)d_in[8],  (const float*)d_in[16], (const float*)d_in[24]};
    const float* c_bt[3] = {(const float*)d_in[9],  (const float*)d_in[17], (const float*)d_in[25]};
    const float* c_w2[3] = {(const float*)d_in[10], (const float*)d_in[18], (const float*)d_in[26]};
    const float* c_b2[3] = {(const float*)d_in[11], (const float*)d_in[19], (const float*)d_in[27]};
    const float* o_w1 = (const float*)d_in[28];
    const float* o_b1 = (const float*)d_in[29];
    const float* o_w2 = (const float*)d_in[30];
    const float* o_b2 = (const float*)d_in[31];

    // ---- workspace layout (~150 MB) ----
    char* wsp = (char*)d_ws;
    size_t used = 0;
    auto alloc = [&](size_t bytes) { char* p = wsp + used; used += (bytes + 255) & ~(size_t)255; return p; };
    int*   counts   = (int*)alloc((size_t)N_NODES_C * 4);
    int*   incl     = (int*)alloc((size_t)N_NODES_C * 4);
    int*   rowstart = (int*)alloc((size_t)N_NODES_C * 4);
    int*   cursor   = (int*)alloc((size_t)N_NODES_C * 4);
    int*   blocksums= (int*)alloc(128 * 4);
    int*   blockoffs= (int*)alloc(128 * 4);
    int*   perm_src = (int*)alloc((size_t)N_EDGES_C * 4);
    _Float16* ea_f16 = (_Float16*)alloc((size_t)N_EDGES_C * 16 * 2);
    _Float16* x16    = (_Float16*)alloc((size_t)N_NODES_C * HID_C * 2);
    _Float16* h16_a  = (_Float16*)alloc((size_t)N_NODES_C * HID_C * 2);
    _Float16* h16_b  = (_Float16*)alloc((size_t)N_NODES_C * HID_C * 2);
    _Float16* x_f16  = (_Float16*)alloc((size_t)N_NODES_C * 64 * 2);
    _Float16* w1t[3], *w2t[3];
    for (int l = 0; l < 3; ++l) {
        w1t[l] = (_Float16*)alloc((size_t)HID_C * HID_C * 2);
        w2t[l] = (_Float16*)alloc((size_t)HID_C * HID_C * 2);
    }
    (void)ws_size;

    // ---- CSR build (once; reused by all 3 layers) ----
    hipMemsetAsync(counts, 0, (size_t)N_NODES_C * 4, stream);
    hist_kernel<<<(N_EDGES_C + 255) / 256, 256, 0, stream>>>(dst, counts, N_EDGES_C);
    scan1_kernel<<<SCAN_NB, SCAN_B, 0, stream>>>(counts, incl, blocksums, N_NODES_C);
    scan2_kernel<<<1, 64, 0, stream>>>(blocksums, blockoffs, SCAN_NB);
    scan3_kernel<<<SCAN_NB, SCAN_B, 0, stream>>>(incl, blockoffs, N_NODES_C);
    initrows_kernel<<<(N_NODES_C + 255) / 256, 256, 0, stream>>>(incl, counts, rowstart,
                                                                 cursor, N_NODES_C);
    scatter_ea_kernel<<<(N_EDGES_C + 255) / 256, 256, 0, stream>>>(
        src, dst, cursor, perm_src, edge_attr, (__half*)ea_f16, N_EDGES_C);
    cast_f16_kernel<<<(N_NODES_C * 64 / 4 + 255) / 256, 256, 0, stream>>>(
        x, x_f16, N_NODES_C * 64 / 4);
    for (int l = 0; l < 3; ++l) {
        const int K1 = (l == 0) ? 64 : HID_C;
        transpose_w_kernel<<<(K1 * HID_C + 255) / 256, 256, 0, stream>>>(
            c_w1[l], w1t[l], K1, HID_C);
        transpose_w_kernel<<<(HID_C * HID_C + 255) / 256, 256, 0, stream>>>(
            c_w2[l], w2t[l], HID_C, HID_C);
    }

    const int n_tiles = N_NODES_C / 16;            // 6250

    // ---- 3 GINE layers (MFMA agg -> MFMA node MLP) ----
    // layer 0 (DIN=64)
    gine_agg_mfma_kernel<64><<<AGG_BLOCKS, 256, 0, stream>>>(
        x_f16, ea_f16, perm_src, rowstart, incl, el_w[0], el_b[0],
        x16, N_NODES_C);
    node_mfma_kernel<64><<<n_tiles, 64, 0, stream>>>(
        x16, w1t[0], c_b1[0], c_g[0], c_bt[0], w2t[0], c_b2[0],
        h16_a, n_tiles);
    // layer 1
    gine_agg_mfma_kernel<128><<<AGG_BLOCKS, 256, 0, stream>>>(
        h16_a, ea_f16, perm_src, rowstart, incl, el_w[1], el_b[1],
        x16, N_NODES_C);
    node_mfma_kernel<128><<<n_tiles, 64, 0, stream>>>(
        x16, w1t[1], c_b1[1], c_g[1], c_bt[1], w2t[1], c_b2[1],
        h16_b, n_tiles);
    // layer 2
    gine_agg_mfma_kernel<128><<<AGG_BLOCKS, 256, 0, stream>>>(
        h16_b, ea_f16, perm_src, rowstart, incl, el_w[2], el_b[2],
        x16, N_NODES_C);
    node_mfma_kernel<128><<<n_tiles, 64, 0, stream>>>(
        x16, w1t[2], c_b1[2], c_g[2], c_bt[2], w2t[2], c_b2[2],
        h16_a, n_tiles);

    // ---- pool + output MLP (reads f16) ----
    pool_kernel<<<N_GRAPHS_C, 256, 0, stream>>>(h16_a, batch, o_w1, o_b1, o_w2, o_b2,
                                                (float*)d_out, N_NODES_C);
}

// Round 11
// 932.907 us; speedup vs baseline: 1.4241x; 1.4241x over previous
//
#include <hip/hip_runtime.h>
#include <hip/hip_fp16.h>
#include <cstdint>
#include <cstddef>

#define N_NODES_C  100000
#define N_EDGES_C  1600000
#define N_GRAPHS_C 256
#define HID_C      128
// 1/sqrt(1+1e-5)
#define BN_SCALE_C 0.9999950000374997f

#define SCAN_B 1024
#define SCAN_NB ((N_NODES_C + SCAN_B - 1) / SCAN_B)   // 98

typedef _Float16 h2 __attribute__((ext_vector_type(2)));
typedef _Float16 h4 __attribute__((ext_vector_type(4)));
typedef _Float16 h8 __attribute__((ext_vector_type(8)));
typedef float    f4 __attribute__((ext_vector_type(4)));

struct __align__(16) EA8 { h2 p[4]; };       // 8 fp16 = 16 B
struct __align__(8)  HQ  { h2 a, b; };       // 4 fp16 = 8 B
struct __align__(16) H8  { __half2 v[4]; };  // preamble convert

#if defined(__has_builtin)
#  if __has_builtin(__builtin_amdgcn_fdot2)
#    define HAVE_FDOT2 1
#  endif
#endif
#ifndef HAVE_FDOT2
#  define HAVE_FDOT2 0
#endif

__device__ __forceinline__ float fdot2_(h2 a, h2 b, float c)
{
#if HAVE_FDOT2
    return __builtin_amdgcn_fdot2(a, b, c, false);
#else
    return c + (float)a[0] * (float)b[0] + (float)a[1] * (float)b[1];
#endif
}

// ---------------------------------------------------------------------------
// CSR build: histogram of dst, inclusive scan, scatter edge ids.
// ---------------------------------------------------------------------------
__global__ __launch_bounds__(256) void hist_kernel(
    const int* __restrict__ dst, int* __restrict__ counts, int n_edges)
{
    int e = blockIdx.x * 256 + threadIdx.x;
    if (e < n_edges) atomicAdd(&counts[dst[e]], 1);
}

__global__ __launch_bounds__(SCAN_B) void scan1_kernel(
    const int* __restrict__ counts, int* __restrict__ incl,
    int* __restrict__ blocksums, int n)
{
    __shared__ int sdata[SCAN_B];
    const int lid = threadIdx.x;
    const int i = blockIdx.x * SCAN_B + lid;
    sdata[lid] = (i < n) ? counts[i] : 0;
    __syncthreads();
#pragma unroll
    for (int off = 1; off < SCAN_B; off <<= 1) {
        int t = (lid >= off) ? sdata[lid - off] : 0;
        __syncthreads();
        sdata[lid] += t;
        __syncthreads();
    }
    if (i < n) incl[i] = sdata[lid];
    if (lid == SCAN_B - 1) blocksums[blockIdx.x] = sdata[lid];
}

__global__ void scan2_kernel(const int* __restrict__ blocksums,
                             int* __restrict__ blockoffs, int nb)
{
    if (threadIdx.x == 0 && blockIdx.x == 0) {
        int off = 0;
        for (int b = 0; b < nb; ++b) { blockoffs[b] = off; off += blocksums[b]; }
    }
}

__global__ __launch_bounds__(SCAN_B) void scan3_kernel(
    int* __restrict__ incl, const int* __restrict__ blockoffs, int n)
{
    const int i = blockIdx.x * SCAN_B + threadIdx.x;
    if (i < n) incl[i] += blockoffs[blockIdx.x];
}

__global__ __launch_bounds__(256) void initrows_kernel(
    const int* __restrict__ incl, const int* __restrict__ counts,
    int* __restrict__ rowstart, int* __restrict__ cursor, int n)
{
    const int i = blockIdx.x * 256 + threadIdx.x;
    if (i < n) {
        const int rs = incl[i] - counts[i];
        rowstart[i] = rs;
        cursor[i]   = rs;
    }
}

// Fused scatter + edge_attr permute/convert: thread e reads its OWN
// edge_attr row (coalesced), converts to f16, writes 32B row to CSR slot.
__global__ __launch_bounds__(256) void scatter_ea_kernel(
    const int* __restrict__ src, const int* __restrict__ dst,
    int* __restrict__ cursor, int* __restrict__ perm_src,
    const float* __restrict__ edge_attr, __half* __restrict__ ea_f16,
    int n_edges)
{
    const int e = blockIdx.x * 256 + threadIdx.x;
    if (e >= n_edges) return;

    const float4* p = (const float4*)(edge_attr + (size_t)e * 16);
    const float4 q0 = p[0], q1 = p[1], q2 = p[2], q3 = p[3];

    const int pos = atomicAdd(&cursor[dst[e]], 1);
    perm_src[pos] = src[e];

    H8 a, b;
    a.v[0] = __floats2half2_rn(q0.x, q0.y);
    a.v[1] = __floats2half2_rn(q0.z, q0.w);
    a.v[2] = __floats2half2_rn(q1.x, q1.y);
    a.v[3] = __floats2half2_rn(q1.z, q1.w);
    b.v[0] = __floats2half2_rn(q2.x, q2.y);
    b.v[1] = __floats2half2_rn(q2.z, q2.w);
    b.v[2] = __floats2half2_rn(q3.x, q3.y);
    b.v[3] = __floats2half2_rn(q3.z, q3.w);
    H8* o = (H8*)(ea_f16 + (size_t)pos * 16);
    o[0] = a;
    o[1] = b;
}

// Cast fp32 array -> f16 (vectorized by 4).
__global__ __launch_bounds__(256) void cast_f16_kernel(
    const float* __restrict__ in, _Float16* __restrict__ out, int n4)
{
    const int i = blockIdx.x * 256 + threadIdx.x;
    if (i >= n4) return;
    const float4 v = ((const float4*)in)[i];
    h4 o; o[0] = (_Float16)v.x; o[1] = (_Float16)v.y;
    o[2] = (_Float16)v.z; o[3] = (_Float16)v.w;
    *(h4*)(out + (size_t)i * 4) = o;
}

// Transpose + cast weights: wt[n][k] = (f16) w[k][n].  (tiny, one-time)
__global__ __launch_bounds__(256) void transpose_w_kernel(
    const float* __restrict__ w, _Float16* __restrict__ wt, int K, int N)
{
    const int i = blockIdx.x * 256 + threadIdx.x;
    if (i >= K * N) return;
    const int n = i / K;
    const int k = i - n * K;
    wt[(size_t)n * K + k] = (_Float16)w[(size_t)k * N + n];
}

// ---------------------------------------------------------------------------
// Edge MLP for one edge (lane's 4 output features) via fdot2; f4 vector ops
// in the epilogue so clang emits v_pk_add_f32 / v_pk_max_f32.
// ---------------------------------------------------------------------------
__device__ __forceinline__ f4 eamlp2(const EA8 a0, const EA8 c0,
                                     const h2 (*ew2h)[4], const f4 ebv)
{
    f4 m = ebv;
#pragma unroll
    for (int k = 0; k < 4; ++k) {
        m[0] = fdot2_(a0.p[k], ew2h[k][0], m[0]);
        m[1] = fdot2_(a0.p[k], ew2h[k][1], m[1]);
        m[2] = fdot2_(a0.p[k], ew2h[k][2], m[2]);
        m[3] = fdot2_(a0.p[k], ew2h[k][3], m[3]);
    }
#pragma unroll
    for (int k = 0; k < 4; ++k) {
        m[0] = fdot2_(c0.p[k], ew2h[4 + k][0], m[0]);
        m[1] = fdot2_(c0.p[k], ew2h[4 + k][1], m[1]);
        m[2] = fdot2_(c0.p[k], ew2h[4 + k][2], m[2]);
        m[3] = fdot2_(c0.p[k], ew2h[4 + k][3], m[3]);
    }
    return m;
}

// relu(m + h_src) accumulated into f32x4 acc with packed vector ops.
__device__ __forceinline__ void edge_acc(const f4 m, const HQ hq, f4& acc)
{
    const f4 hv = { (float)hq.a[0], (float)hq.a[1],
                    (float)hq.b[0], (float)hq.b[1] };
    f4 s = m + hv;
    const f4 z = {0.f, 0.f, 0.f, 0.f};
    s = __builtin_elementwise_max(s, z);
    acc += s;
}

// ---------------------------------------------------------------------------
// CSR aggregate -- round-9 verified structure (144 us @ DIN=128):
// one node per 32/16-lane slot, no barriers; flat ILP-4 main loop with
// loads in consumption order (perm4 -> ea8 -> hq4) so edge-MLP compute
// overlaps the in-flight h-gathers; 2/1-wide tails.
// Adds residual h_v and writes x16 = h+agg as f16.
// ---------------------------------------------------------------------------
template<int DIN>
__global__ __launch_bounds__(256) void gine_agg_kernel(
    const _Float16* __restrict__ hin, const _Float16* __restrict__ ea16,
    const int* __restrict__ perm_src,
    const int* __restrict__ rowstart, const int* __restrict__ rowend,
    const float* __restrict__ ew, const float* __restrict__ eb,
    _Float16* __restrict__ x16, int n_nodes)
{
    constexpr int NQ    = DIN / 4;
    constexpr int SLOTS = 256 / NQ;
    const int fq   = threadIdx.x & (NQ - 1);
    const int slot = threadIdx.x / NQ;
    const int v = blockIdx.x * SLOTS + slot;
    if (v >= n_nodes) return;

    h2 ew2h[8][4];
#pragma unroll
    for (int k2 = 0; k2 < 8; ++k2)
#pragma unroll
        for (int fi = 0; fi < 4; ++fi) {
            h2 t;
            t[0] = (_Float16)ew[(size_t)(2 * k2)     * DIN + fq * 4 + fi];
            t[1] = (_Float16)ew[(size_t)(2 * k2 + 1) * DIN + fq * 4 + fi];
            ew2h[k2][fi] = t;
        }
    const f4 ebv = *(const f4*)(eb + fq * 4);

    const int s0 = rowstart[v];
    const int s1 = rowend[v];

    f4 acc = {0.f, 0.f, 0.f, 0.f};
    int j = s0;

    // ---- 4-wide: loads issued up front, in consumption order ----
    for (; j + 4 <= s1; j += 4) {
        const int sn0 = perm_src[j + 0];
        const int sn1 = perm_src[j + 1];
        const int sn2 = perm_src[j + 2];
        const int sn3 = perm_src[j + 3];
        const EA8* pe = (const EA8*)(ea16 + (size_t)j * 16);
        const EA8 a0 = pe[0], c0 = pe[1], a1 = pe[2], c1 = pe[3];
        const EA8 a2 = pe[4], c2 = pe[5], a3 = pe[6], c3 = pe[7];
        const HQ hq0 = *(const HQ*)(hin + (size_t)sn0 * DIN + fq * 4);
        const HQ hq1 = *(const HQ*)(hin + (size_t)sn1 * DIN + fq * 4);
        const HQ hq2 = *(const HQ*)(hin + (size_t)sn2 * DIN + fq * 4);
        const HQ hq3 = *(const HQ*)(hin + (size_t)sn3 * DIN + fq * 4);

        const f4 m0 = eamlp2(a0, c0, ew2h, ebv);
        const f4 m1 = eamlp2(a1, c1, ew2h, ebv);
        const f4 m2 = eamlp2(a2, c2, ew2h, ebv);
        const f4 m3 = eamlp2(a3, c3, ew2h, ebv);

        edge_acc(m0, hq0, acc);
        edge_acc(m1, hq1, acc);
        edge_acc(m2, hq2, acc);
        edge_acc(m3, hq3, acc);
    }
    // ---- 2-wide remainder ----
    if (j + 2 <= s1) {
        const int sn0 = perm_src[j + 0];
        const int sn1 = perm_src[j + 1];
        const EA8* pe = (const EA8*)(ea16 + (size_t)j * 16);
        const EA8 a0 = pe[0], c0 = pe[1], a1 = pe[2], c1 = pe[3];
        const HQ hq0 = *(const HQ*)(hin + (size_t)sn0 * DIN + fq * 4);
        const HQ hq1 = *(const HQ*)(hin + (size_t)sn1 * DIN + fq * 4);
        const f4 m0 = eamlp2(a0, c0, ew2h, ebv);
        const f4 m1 = eamlp2(a1, c1, ew2h, ebv);
        edge_acc(m0, hq0, acc);
        edge_acc(m1, hq1, acc);
        j += 2;
    }
    // ---- 1-wide remainder ----
    if (j < s1) {
        const int sn = perm_src[j];
        const EA8* pe = (const EA8*)(ea16 + (size_t)j * 16);
        const EA8 a0 = pe[0], c0 = pe[1];
        const HQ hq = *(const HQ*)(hin + (size_t)sn * DIN + fq * 4);
        const f4 m0 = eamlp2(a0, c0, ew2h, ebv);
        edge_acc(m0, hq, acc);
    }

    // residual + f16 store: x = h_v + agg
    const HQ hv = *(const HQ*)(hin + (size_t)v * DIN + fq * 4);
    h4 o;
    o[0] = (_Float16)(acc[0] + (float)hv.a[0]);
    o[1] = (_Float16)(acc[1] + (float)hv.a[1]);
    o[2] = (_Float16)(acc[2] + (float)hv.b[0]);
    o[3] = (_Float16)(acc[3] + (float)hv.b[1]);
    *(h4*)(x16 + (size_t)v * DIN + fq * 4) = o;
}

// ---------------------------------------------------------------------------
// Node MLP: 1 wave per block, 1 16-node tile (round-9 verified structure).
// A-fragments for mm1 read DIRECTLY from global x16 (f16); s_t LDS only for
// the mm1->mm2 transpose. Always writes f16 h (pool reads f16).
// ---------------------------------------------------------------------------
template<int DIN>
__global__ __launch_bounds__(64) void node_mfma_kernel(
    const _Float16* __restrict__ x16,
    const _Float16* __restrict__ w1t, const float* __restrict__ b1,
    const float* __restrict__ gm, const float* __restrict__ bt,
    const _Float16* __restrict__ w2t, const float* __restrict__ b2,
    _Float16* __restrict__ h16out, int n_tiles)
{
    constexpr int STP = HID_C + 8;
    __shared__ _Float16 s_t[16][STP];

    const int lane = threadIdx.x;
    const int tile = blockIdx.x;
    const int node0 = tile * 16;
    const int ln   = lane & 15;
    const int quad = lane >> 4;

    constexpr int NKS = DIN / 32;
    h8 af[NKS];
#pragma unroll
    for (int ks = 0; ks < NKS; ++ks)
        af[ks] = *(const h8*)(x16 + (size_t)(node0 + ln) * DIN + ks * 32 + quad * 8);

    // ---- mm1 + BN + relu -> s_t (f16) ----
#pragma unroll
    for (int nt = 0; nt < 8; ++nt) {
        const int col = nt * 16 + ln;
        const float bv = b1[col];
        f4 acc = {bv, bv, bv, bv};
#pragma unroll
        for (int ks = 0; ks < NKS; ++ks) {
            const h8 bf = *(const h8*)(w1t + (size_t)col * DIN + ks * 32 + quad * 8);
            acc = __builtin_amdgcn_mfma_f32_16x16x32_f16(af[ks], bf, acc, 0, 0, 0);
        }
        const float gv = gm[col], btv = bt[col];
#pragma unroll
        for (int r = 0; r < 4; ++r) {
            const float t = fmaxf(fmaf(acc[r] * BN_SCALE_C, gv, btv), 0.f);
            s_t[quad * 4 + r][col] = (_Float16)t;
        }
    }
    __syncthreads();

    h8 af2[4];
#pragma unroll
    for (int ks = 0; ks < 4; ++ks)
        af2[ks] = *(const h8*)&s_t[ln][ks * 32 + quad * 8];

    // ---- mm2 + relu -> h16 ----
#pragma unroll
    for (int nt = 0; nt < 8; ++nt) {
        const int col = nt * 16 + ln;
        const float bv = b2[col];
        f4 acc = {bv, bv, bv, bv};
#pragma unroll
        for (int ks = 0; ks < 4; ++ks) {
            const h8 bf = *(const h8*)(w2t + (size_t)col * HID_C + ks * 32 + quad * 8);
            acc = __builtin_amdgcn_mfma_f32_16x16x32_f16(af2[ks], bf, acc, 0, 0, 0);
        }
#pragma unroll
        for (int r = 0; r < 4; ++r) {
            const int node = node0 + quad * 4 + r;
            h16out[(size_t)node * HID_C + col] = (_Float16)fmaxf(acc[r], 0.f);
        }
    }
}

// ---------------------------------------------------------------------------
// Pool + output MLP; reads the final f16 h.
// ---------------------------------------------------------------------------
__global__ __launch_bounds__(256) void pool_kernel(
    const _Float16* __restrict__ hfin, const int* __restrict__ batch,
    const float* __restrict__ w1, const float* __restrict__ b1,
    const float* __restrict__ w2, const float* __restrict__ b2,
    float* __restrict__ out, int n_nodes)
{
    const int gid = blockIdx.x;

    int lo = 0, hi = n_nodes;
    while (lo < hi) { int mid = (lo + hi) >> 1; if (batch[mid] < gid) lo = mid + 1; else hi = mid; }
    const int start = lo;
    hi = n_nodes;
    while (lo < hi) { int mid = (lo + hi) >> 1; if (batch[mid] < gid + 1) lo = mid + 1; else hi = mid; }
    const int end = lo;

    const int f = threadIdx.x & (HID_C - 1);
    const int half = threadIdx.x >> 7;

    float sum = 0.f;
    for (int n = start + half; n < end; n += 2)
        sum += (float)hfin[(size_t)n * HID_C + f];

    __shared__ float s_sum[2][HID_C];
    __shared__ float s_p[HID_C];
    __shared__ float s_t[HID_C];
    s_sum[half][f] = sum;
    __syncthreads();

    if (threadIdx.x < HID_C) {
        const float cnt = (float)(end - start);
        s_p[f] = (s_sum[0][f] + s_sum[1][f]) / fmaxf(cnt, 1.f);
    }
    __syncthreads();

    if (threadIdx.x < HID_C) {
        float acc = b1[f];
        for (int k = 0; k < HID_C; ++k) acc = fmaf(s_p[k], w1[k * HID_C + f], acc);
        s_t[f] = fmaxf(acc, 0.f);
    }
    __syncthreads();

    if (threadIdx.x < HID_C) {
        float acc = b2[f];
        for (int k = 0; k < HID_C; ++k) acc = fmaf(s_t[k], w2[k * HID_C + f], acc);
        out[(size_t)gid * HID_C + f] = acc;
    }
}

// ---------------------------------------------------------------------------
extern "C" void kernel_launch(void* const* d_in, const int* in_sizes, int n_in,
                              void* d_out, int out_size, void* d_ws, size_t ws_size,
                              hipStream_t stream)
{
    const float* x         = (const float*)d_in[0];
    const float* edge_attr = (const float*)d_in[1];
    const int*   edge_index= (const int*)  d_in[2];
    const int*   batch     = (const int*)  d_in[3];
    const int*   src = edge_index;
    const int*   dst = edge_index + N_EDGES_C;

    const float* el_w[3] = {(const float*)d_in[4],  (const float*)d_in[12], (const float*)d_in[20]};
    const float* el_b[3] = {(const float*)d_in[5],  (const float*)d_in[13], (const float*)d_in[21]};
    const float* c_w1[3] = {(const float*)d_in[6],  (const float*)d_in[14], (const float*)d_in[22]};
    const float* c_b1[3] = {(const float*)d_in[7],  (const float*)d_in[15], (const float*)d_in[23]};
    const float* c_g [3] = {(const float*)d_in[8],  (const float*)d_in[16], (const float*)d_in[24]};
    const float* c_bt[3] = {(const float*)d_in[9],  (const float*)d_in[17], (const float*)d_in[25]};
    const float* c_w2[3] = {(const float*)d_in[10], (const float*)d_in[18], (const float*)d_in[26]};
    const float* c_b2[3] = {(const float*)d_in[11], (const float*)d_in[19], (const float*)d_in[27]};
    const float* o_w1 = (const float*)d_in[28];
    const float* o_b1 = (const float*)d_in[29];
    const float* o_w2 = (const float*)d_in[30];
    const float* o_b2 = (const float*)d_in[31];

    // ---- workspace layout (~150 MB) ----
    char* wsp = (char*)d_ws;
    size_t used = 0;
    auto alloc = [&](size_t bytes) { char* p = wsp + used; used += (bytes + 255) & ~(size_t)255; return p; };
    int*   counts   = (int*)alloc((size_t)N_NODES_C * 4);
    int*   incl     = (int*)alloc((size_t)N_NODES_C * 4);
    int*   rowstart = (int*)alloc((size_t)N_NODES_C * 4);
    int*   cursor   = (int*)alloc((size_t)N_NODES_C * 4);
    int*   blocksums= (int*)alloc(128 * 4);
    int*   blockoffs= (int*)alloc(128 * 4);
    int*   perm_src = (int*)alloc((size_t)N_EDGES_C * 4);
    _Float16* ea_f16 = (_Float16*)alloc((size_t)N_EDGES_C * 16 * 2);
    _Float16* x16    = (_Float16*)alloc((size_t)N_NODES_C * HID_C * 2);
    _Float16* h16_a  = (_Float16*)alloc((size_t)N_NODES_C * HID_C * 2);
    _Float16* h16_b  = (_Float16*)alloc((size_t)N_NODES_C * HID_C * 2);
    _Float16* x_f16  = (_Float16*)alloc((size_t)N_NODES_C * 64 * 2);
    _Float16* w1t[3], *w2t[3];
    for (int l = 0; l < 3; ++l) {
        w1t[l] = (_Float16*)alloc((size_t)HID_C * HID_C * 2);
        w2t[l] = (_Float16*)alloc((size_t)HID_C * HID_C * 2);
    }
    (void)ws_size;

    // ---- CSR build (once; reused by all 3 layers) ----
    hipMemsetAsync(counts, 0, (size_t)N_NODES_C * 4, stream);
    hist_kernel<<<(N_EDGES_C + 255) / 256, 256, 0, stream>>>(dst, counts, N_EDGES_C);
    scan1_kernel<<<SCAN_NB, SCAN_B, 0, stream>>>(counts, incl, blocksums, N_NODES_C);
    scan2_kernel<<<1, 64, 0, stream>>>(blocksums, blockoffs, SCAN_NB);
    scan3_kernel<<<SCAN_NB, SCAN_B, 0, stream>>>(incl, blockoffs, N_NODES_C);
    initrows_kernel<<<(N_NODES_C + 255) / 256, 256, 0, stream>>>(incl, counts, rowstart,
                                                                 cursor, N_NODES_C);
    scatter_ea_kernel<<<(N_EDGES_C + 255) / 256, 256, 0, stream>>>(
        src, dst, cursor, perm_src, edge_attr, (__half*)ea_f16, N_EDGES_C);
    cast_f16_kernel<<<(N_NODES_C * 64 / 4 + 255) / 256, 256, 0, stream>>>(
        x, x_f16, N_NODES_C * 64 / 4);
    for (int l = 0; l < 3; ++l) {
        const int K1 = (l == 0) ? 64 : HID_C;
        transpose_w_kernel<<<(K1 * HID_C + 255) / 256, 256, 0, stream>>>(
            c_w1[l], w1t[l], K1, HID_C);
        transpose_w_kernel<<<(HID_C * HID_C + 255) / 256, 256, 0, stream>>>(
            c_w2[l], w2t[l], HID_C, HID_C);
    }

    const int n_tiles = N_NODES_C / 16;            // 6250

    // ---- 3 GINE layers (split: high-TLP agg -> tiny MFMA node MLP) ----
    // layer 0 (DIN=64)
    gine_agg_kernel<64><<<(N_NODES_C + 15) / 16, 256, 0, stream>>>(
        x_f16, ea_f16, perm_src, rowstart, incl, el_w[0], el_b[0],
        x16, N_NODES_C);
    node_mfma_kernel<64><<<n_tiles, 64, 0, stream>>>(
        x16, w1t[0], c_b1[0], c_g[0], c_bt[0], w2t[0], c_b2[0],
        h16_a, n_tiles);
    // layer 1
    gine_agg_kernel<128><<<(N_NODES_C + 7) / 8, 256, 0, stream>>>(
        h16_a, ea_f16, perm_src, rowstart, incl, el_w[1], el_b[1],
        x16, N_NODES_C);
    node_mfma_kernel<128><<<n_tiles, 64, 0, stream>>>(
        x16, w1t[1], c_b1[1], c_g[1], c_bt[1], w2t[1], c_b2[1],
        h16_b, n_tiles);
    // layer 2
    gine_agg_kernel<128><<<(N_NODES_C + 7) / 8, 256, 0, stream>>>(
        h16_b, ea_f16, perm_src, rowstart, incl, el_w[2], el_b[2],
        x16, N_NODES_C);
    node_mfma_kernel<128><<<n_tiles, 64, 0, stream>>>(
        x16, w1t[2], c_b1[2], c_g[2], c_bt[2], w2t[2], c_b2[2],
        h16_a, n_tiles);

    // ---- pool + output MLP (reads f16) ----
    pool_kernel<<<N_GRAPHS_C, 256, 0, stream>>>(h16_a, batch, o_w1, o_b1, o_w2, o_b2,
                                                (float*)d_out, N_NODES_C);
}

// Round 12
// 930.624 us; speedup vs baseline: 1.4275x; 1.0025x over previous
//
#include <hip/hip_runtime.h>
#include <hip/hip_fp16.h>
#include <cstdint>
#include <cstddef>

#define N_NODES_C  100000
#define N_EDGES_C  1600000
#define N_GRAPHS_C 256
#define HID_C      128
// 1/sqrt(1+1e-5)
#define BN_SCALE_C 0.9999950000374997f

#define SCAN_B 1024
#define SCAN_NB ((N_NODES_C + SCAN_B - 1) / SCAN_B)   // 98

typedef _Float16 h2 __attribute__((ext_vector_type(2)));
typedef _Float16 h4 __attribute__((ext_vector_type(4)));
typedef _Float16 h8 __attribute__((ext_vector_type(8)));
typedef float    f4 __attribute__((ext_vector_type(4)));

struct __align__(16) EA8 { h2 p[4]; };       // 8 fp16 = 16 B
struct __align__(8)  HQ  { h2 a, b; };       // 4 fp16 = 8 B
struct __align__(16) H8  { __half2 v[4]; };  // preamble convert

#if defined(__has_builtin)
#  if __has_builtin(__builtin_amdgcn_fdot2)
#    define HAVE_FDOT2 1
#  endif
#endif
#ifndef HAVE_FDOT2
#  define HAVE_FDOT2 0
#endif

__device__ __forceinline__ float fdot2_(h2 a, h2 b, float c)
{
#if HAVE_FDOT2
    return __builtin_amdgcn_fdot2(a, b, c, false);
#else
    return c + (float)a[0] * (float)b[0] + (float)a[1] * (float)b[1];
#endif
}

// ---------------------------------------------------------------------------
// CSR build: histogram of dst, inclusive scan, scatter edge ids.
// ---------------------------------------------------------------------------
__global__ __launch_bounds__(256) void hist_kernel(
    const int* __restrict__ dst, int* __restrict__ counts, int n_edges)
{
    int e = blockIdx.x * 256 + threadIdx.x;
    if (e < n_edges) atomicAdd(&counts[dst[e]], 1);
}

__global__ __launch_bounds__(SCAN_B) void scan1_kernel(
    const int* __restrict__ counts, int* __restrict__ incl,
    int* __restrict__ blocksums, int n)
{
    __shared__ int sdata[SCAN_B];
    const int lid = threadIdx.x;
    const int i = blockIdx.x * SCAN_B + lid;
    sdata[lid] = (i < n) ? counts[i] : 0;
    __syncthreads();
#pragma unroll
    for (int off = 1; off < SCAN_B; off <<= 1) {
        int t = (lid >= off) ? sdata[lid - off] : 0;
        __syncthreads();
        sdata[lid] += t;
        __syncthreads();
    }
    if (i < n) incl[i] = sdata[lid];
    if (lid == SCAN_B - 1) blocksums[blockIdx.x] = sdata[lid];
}

// scan3 with folded block-offset computation (replaces scan2+scan3):
// every thread of block b sums blocksums[0..b) (scalar L2-hit loads, <=97).
__global__ __launch_bounds__(SCAN_B) void scan3_kernel(
    int* __restrict__ incl, const int* __restrict__ blocksums, int n)
{
    int off = 0;
    for (int b = 0; b < (int)blockIdx.x; ++b) off += blocksums[b];
    const int i = blockIdx.x * SCAN_B + threadIdx.x;
    if (i < n) incl[i] += off;
}

__global__ __launch_bounds__(256) void initrows_kernel(
    const int* __restrict__ incl, const int* __restrict__ counts,
    int* __restrict__ rowstart, int* __restrict__ cursor, int n)
{
    const int i = blockIdx.x * 256 + threadIdx.x;
    if (i < n) {
        const int rs = incl[i] - counts[i];
        rowstart[i] = rs;
        cursor[i]   = rs;
    }
}

// Fused scatter + edge_attr permute/convert: thread e reads its OWN
// edge_attr row (coalesced), converts to f16, writes 32B row to CSR slot.
__global__ __launch_bounds__(256) void scatter_ea_kernel(
    const int* __restrict__ src, const int* __restrict__ dst,
    int* __restrict__ cursor, int* __restrict__ perm_src,
    const float* __restrict__ edge_attr, __half* __restrict__ ea_f16,
    int n_edges)
{
    const int e = blockIdx.x * 256 + threadIdx.x;
    if (e >= n_edges) return;

    const float4* p = (const float4*)(edge_attr + (size_t)e * 16);
    const float4 q0 = p[0], q1 = p[1], q2 = p[2], q3 = p[3];

    const int pos = atomicAdd(&cursor[dst[e]], 1);
    perm_src[pos] = src[e];

    H8 a, b;
    a.v[0] = __floats2half2_rn(q0.x, q0.y);
    a.v[1] = __floats2half2_rn(q0.z, q0.w);
    a.v[2] = __floats2half2_rn(q1.x, q1.y);
    a.v[3] = __floats2half2_rn(q1.z, q1.w);
    b.v[0] = __floats2half2_rn(q2.x, q2.y);
    b.v[1] = __floats2half2_rn(q2.z, q2.w);
    b.v[2] = __floats2half2_rn(q3.x, q3.y);
    b.v[3] = __floats2half2_rn(q3.z, q3.w);
    H8* o = (H8*)(ea_f16 + (size_t)pos * 16);
    o[0] = a;
    o[1] = b;
}

// Cast fp32 array -> f16 (vectorized by 4).
__global__ __launch_bounds__(256) void cast_f16_kernel(
    const float* __restrict__ in, _Float16* __restrict__ out, int n4)
{
    const int i = blockIdx.x * 256 + threadIdx.x;
    if (i >= n4) return;
    const float4 v = ((const float4*)in)[i];
    h4 o; o[0] = (_Float16)v.x; o[1] = (_Float16)v.y;
    o[2] = (_Float16)v.z; o[3] = (_Float16)v.w;
    *(h4*)(out + (size_t)i * 4) = o;
}

// All 6 weight transposes fused into one launch. Segment table built on
// host; item i -> segment s (6 segments), local index -> (n,k).
struct WSeg { const float* w; _Float16* wt; int K, N, base; };

__global__ __launch_bounds__(256) void transpose_all_kernel(
    WSeg s0, WSeg s1, WSeg s2, WSeg s3, WSeg s4, WSeg s5, int total)
{
    int i = blockIdx.x * 256 + threadIdx.x;
    if (i >= total) return;
    WSeg s;
    if      (i >= s5.base) s = s5;
    else if (i >= s4.base) s = s4;
    else if (i >= s3.base) s = s3;
    else if (i >= s2.base) s = s2;
    else if (i >= s1.base) s = s1;
    else                   s = s0;
    const int li = i - s.base;
    const int n = li / s.K;
    const int k = li - n * s.K;
    s.wt[(size_t)n * s.K + k] = (_Float16)s.w[(size_t)k * s.N + n];
}

// ---------------------------------------------------------------------------
// Edge MLP for one edge (lane's 4 output features) via fdot2; f4 vector ops
// in the epilogue so clang emits packed f32 adds/maxes.
// ---------------------------------------------------------------------------
__device__ __forceinline__ f4 eamlp2(const EA8 a0, const EA8 c0,
                                     const h2 (*ew2h)[4], const f4 ebv)
{
    f4 m = ebv;
#pragma unroll
    for (int k = 0; k < 4; ++k) {
        m[0] = fdot2_(a0.p[k], ew2h[k][0], m[0]);
        m[1] = fdot2_(a0.p[k], ew2h[k][1], m[1]);
        m[2] = fdot2_(a0.p[k], ew2h[k][2], m[2]);
        m[3] = fdot2_(a0.p[k], ew2h[k][3], m[3]);
    }
#pragma unroll
    for (int k = 0; k < 4; ++k) {
        m[0] = fdot2_(c0.p[k], ew2h[4 + k][0], m[0]);
        m[1] = fdot2_(c0.p[k], ew2h[4 + k][1], m[1]);
        m[2] = fdot2_(c0.p[k], ew2h[4 + k][2], m[2]);
        m[3] = fdot2_(c0.p[k], ew2h[4 + k][3], m[3]);
    }
    return m;
}

// relu(m + h_src) accumulated into f32x4 acc with packed vector ops.
__device__ __forceinline__ void edge_acc(const f4 m, const HQ hq, f4& acc)
{
    const f4 hv = { (float)hq.a[0], (float)hq.a[1],
                    (float)hq.b[0], (float)hq.b[1] };
    f4 s = m + hv;
    const f4 z = {0.f, 0.f, 0.f, 0.f};
    s = __builtin_elementwise_max(s, z);
    acc += s;
}

// ---------------------------------------------------------------------------
// CSR aggregate -- round-9 verified structure, ILP deepened 4->6:
// one node per 32/16-lane slot, no barriers; flat 6-wide main loop with
// loads in consumption order (perm6 -> ea12 -> hq6) so edge-MLP compute
// overlaps the in-flight h-gathers; 4/2/1 tails.
// Adds residual h_v and writes x16 = h+agg as f16.
// ---------------------------------------------------------------------------
template<int DIN>
__global__ __launch_bounds__(256) void gine_agg_kernel(
    const _Float16* __restrict__ hin, const _Float16* __restrict__ ea16,
    const int* __restrict__ perm_src,
    const int* __restrict__ rowstart, const int* __restrict__ rowend,
    const float* __restrict__ ew, const float* __restrict__ eb,
    _Float16* __restrict__ x16, int n_nodes)
{
    constexpr int NQ    = DIN / 4;
    constexpr int SLOTS = 256 / NQ;
    const int fq   = threadIdx.x & (NQ - 1);
    const int slot = threadIdx.x / NQ;
    const int v = blockIdx.x * SLOTS + slot;
    if (v >= n_nodes) return;

    h2 ew2h[8][4];
#pragma unroll
    for (int k2 = 0; k2 < 8; ++k2)
#pragma unroll
        for (int fi = 0; fi < 4; ++fi) {
            h2 t;
            t[0] = (_Float16)ew[(size_t)(2 * k2)     * DIN + fq * 4 + fi];
            t[1] = (_Float16)ew[(size_t)(2 * k2 + 1) * DIN + fq * 4 + fi];
            ew2h[k2][fi] = t;
        }
    const f4 ebv = *(const f4*)(eb + fq * 4);

    const int s0 = rowstart[v];
    const int s1 = rowend[v];

    f4 acc = {0.f, 0.f, 0.f, 0.f};
    int j = s0;

    // ---- 6-wide: loads issued up front, in consumption order ----
    for (; j + 6 <= s1; j += 6) {
        const int sn0 = perm_src[j + 0];
        const int sn1 = perm_src[j + 1];
        const int sn2 = perm_src[j + 2];
        const int sn3 = perm_src[j + 3];
        const int sn4 = perm_src[j + 4];
        const int sn5 = perm_src[j + 5];
        const EA8* pe = (const EA8*)(ea16 + (size_t)j * 16);
        const EA8 a0 = pe[0],  c0 = pe[1],  a1 = pe[2],  c1 = pe[3];
        const EA8 a2 = pe[4],  c2 = pe[5],  a3 = pe[6],  c3 = pe[7];
        const EA8 a4 = pe[8],  c4 = pe[9],  a5 = pe[10], c5 = pe[11];
        const HQ hq0 = *(const HQ*)(hin + (size_t)sn0 * DIN + fq * 4);
        const HQ hq1 = *(const HQ*)(hin + (size_t)sn1 * DIN + fq * 4);
        const HQ hq2 = *(const HQ*)(hin + (size_t)sn2 * DIN + fq * 4);
        const HQ hq3 = *(const HQ*)(hin + (size_t)sn3 * DIN + fq * 4);
        const HQ hq4 = *(const HQ*)(hin + (size_t)sn4 * DIN + fq * 4);
        const HQ hq5 = *(const HQ*)(hin + (size_t)sn5 * DIN + fq * 4);

        const f4 m0 = eamlp2(a0, c0, ew2h, ebv);
        const f4 m1 = eamlp2(a1, c1, ew2h, ebv);
        const f4 m2 = eamlp2(a2, c2, ew2h, ebv);
        const f4 m3 = eamlp2(a3, c3, ew2h, ebv);
        const f4 m4 = eamlp2(a4, c4, ew2h, ebv);
        const f4 m5 = eamlp2(a5, c5, ew2h, ebv);

        edge_acc(m0, hq0, acc);
        edge_acc(m1, hq1, acc);
        edge_acc(m2, hq2, acc);
        edge_acc(m3, hq3, acc);
        edge_acc(m4, hq4, acc);
        edge_acc(m5, hq5, acc);
    }
    // ---- 4-wide remainder ----
    if (j + 4 <= s1) {
        const int sn0 = perm_src[j + 0];
        const int sn1 = perm_src[j + 1];
        const int sn2 = perm_src[j + 2];
        const int sn3 = perm_src[j + 3];
        const EA8* pe = (const EA8*)(ea16 + (size_t)j * 16);
        const EA8 a0 = pe[0], c0 = pe[1], a1 = pe[2], c1 = pe[3];
        const EA8 a2 = pe[4], c2 = pe[5], a3 = pe[6], c3 = pe[7];
        const HQ hq0 = *(const HQ*)(hin + (size_t)sn0 * DIN + fq * 4);
        const HQ hq1 = *(const HQ*)(hin + (size_t)sn1 * DIN + fq * 4);
        const HQ hq2 = *(const HQ*)(hin + (size_t)sn2 * DIN + fq * 4);
        const HQ hq3 = *(const HQ*)(hin + (size_t)sn3 * DIN + fq * 4);
        const f4 m0 = eamlp2(a0, c0, ew2h, ebv);
        const f4 m1 = eamlp2(a1, c1, ew2h, ebv);
        const f4 m2 = eamlp2(a2, c2, ew2h, ebv);
        const f4 m3 = eamlp2(a3, c3, ew2h, ebv);
        edge_acc(m0, hq0, acc);
        edge_acc(m1, hq1, acc);
        edge_acc(m2, hq2, acc);
        edge_acc(m3, hq3, acc);
        j += 4;
    }
    // ---- 2-wide remainder ----
    if (j + 2 <= s1) {
        const int sn0 = perm_src[j + 0];
        const int sn1 = perm_src[j + 1];
        const EA8* pe = (const EA8*)(ea16 + (size_t)j * 16);
        const EA8 a0 = pe[0], c0 = pe[1], a1 = pe[2], c1 = pe[3];
        const HQ hq0 = *(const HQ*)(hin + (size_t)sn0 * DIN + fq * 4);
        const HQ hq1 = *(const HQ*)(hin + (size_t)sn1 * DIN + fq * 4);
        const f4 m0 = eamlp2(a0, c0, ew2h, ebv);
        const f4 m1 = eamlp2(a1, c1, ew2h, ebv);
        edge_acc(m0, hq0, acc);
        edge_acc(m1, hq1, acc);
        j += 2;
    }
    // ---- 1-wide remainder ----
    if (j < s1) {
        const int sn = perm_src[j];
        const EA8* pe = (const EA8*)(ea16 + (size_t)j * 16);
        const EA8 a0 = pe[0], c0 = pe[1];
        const HQ hq = *(const HQ*)(hin + (size_t)sn * DIN + fq * 4);
        const f4 m0 = eamlp2(a0, c0, ew2h, ebv);
        edge_acc(m0, hq, acc);
    }

    // residual + f16 store: x = h_v + agg
    const HQ hv = *(const HQ*)(hin + (size_t)v * DIN + fq * 4);
    h4 o;
    o[0] = (_Float16)(acc[0] + (float)hv.a[0]);
    o[1] = (_Float16)(acc[1] + (float)hv.a[1]);
    o[2] = (_Float16)(acc[2] + (float)hv.b[0]);
    o[3] = (_Float16)(acc[3] + (float)hv.b[1]);
    *(h4*)(x16 + (size_t)v * DIN + fq * 4) = o;
}

// ---------------------------------------------------------------------------
// Node MLP: 1 wave per block, 1 16-node tile (round-9 verified structure).
// A-fragments for mm1 read DIRECTLY from global x16 (f16); s_t LDS only for
// the mm1->mm2 transpose. Always writes f16 h (pool reads f16).
// ---------------------------------------------------------------------------
template<int DIN>
__global__ __launch_bounds__(64) void node_mfma_kernel(
    const _Float16* __restrict__ x16,
    const _Float16* __restrict__ w1t, const float* __restrict__ b1,
    const float* __restrict__ gm, const float* __restrict__ bt,
    const _Float16* __restrict__ w2t, const float* __restrict__ b2,
    _Float16* __restrict__ h16out, int n_tiles)
{
    constexpr int STP = HID_C + 8;
    __shared__ _Float16 s_t[16][STP];

    const int lane = threadIdx.x;
    const int tile = blockIdx.x;
    const int node0 = tile * 16;
    const int ln   = lane & 15;
    const int quad = lane >> 4;

    constexpr int NKS = DIN / 32;
    h8 af[NKS];
#pragma unroll
    for (int ks = 0; ks < NKS; ++ks)
        af[ks] = *(const h8*)(x16 + (size_t)(node0 + ln) * DIN + ks * 32 + quad * 8);

    // ---- mm1 + BN + relu -> s_t (f16) ----
#pragma unroll
    for (int nt = 0; nt < 8; ++nt) {
        const int col = nt * 16 + ln;
        const float bv = b1[col];
        f4 acc = {bv, bv, bv, bv};
#pragma unroll
        for (int ks = 0; ks < NKS; ++ks) {
            const h8 bf = *(const h8*)(w1t + (size_t)col * DIN + ks * 32 + quad * 8);
            acc = __builtin_amdgcn_mfma_f32_16x16x32_f16(af[ks], bf, acc, 0, 0, 0);
        }
        const float gv = gm[col], btv = bt[col];
#pragma unroll
        for (int r = 0; r < 4; ++r) {
            const float t = fmaxf(fmaf(acc[r] * BN_SCALE_C, gv, btv), 0.f);
            s_t[quad * 4 + r][col] = (_Float16)t;
        }
    }
    __syncthreads();

    h8 af2[4];
#pragma unroll
    for (int ks = 0; ks < 4; ++ks)
        af2[ks] = *(const h8*)&s_t[ln][ks * 32 + quad * 8];

    // ---- mm2 + relu -> h16 ----
#pragma unroll
    for (int nt = 0; nt < 8; ++nt) {
        const int col = nt * 16 + ln;
        const float bv = b2[col];
        f4 acc = {bv, bv, bv, bv};
#pragma unroll
        for (int ks = 0; ks < 4; ++ks) {
            const h8 bf = *(const h8*)(w2t + (size_t)col * HID_C + ks * 32 + quad * 8);
            acc = __builtin_amdgcn_mfma_f32_16x16x32_f16(af2[ks], bf, acc, 0, 0, 0);
        }
#pragma unroll
        for (int r = 0; r < 4; ++r) {
            const int node = node0 + quad * 4 + r;
            h16out[(size_t)node * HID_C + col] = (_Float16)fmaxf(acc[r], 0.f);
        }
    }
}

// ---------------------------------------------------------------------------
// Pool + output MLP; reads the final f16 h.
// ---------------------------------------------------------------------------
__global__ __launch_bounds__(256) void pool_kernel(
    const _Float16* __restrict__ hfin, const int* __restrict__ batch,
    const float* __restrict__ w1, const float* __restrict__ b1,
    const float* __restrict__ w2, const float* __restrict__ b2,
    float* __restrict__ out, int n_nodes)
{
    const int gid = blockIdx.x;

    int lo = 0, hi = n_nodes;
    while (lo < hi) { int mid = (lo + hi) >> 1; if (batch[mid] < gid) lo = mid + 1; else hi = mid; }
    const int start = lo;
    hi = n_nodes;
    while (lo < hi) { int mid = (lo + hi) >> 1; if (batch[mid] < gid + 1) lo = mid + 1; else hi = mid; }
    const int end = lo;

    const int f = threadIdx.x & (HID_C - 1);
    const int half = threadIdx.x >> 7;

    float sum = 0.f;
    for (int n = start + half; n < end; n += 2)
        sum += (float)hfin[(size_t)n * HID_C + f];

    __shared__ float s_sum[2][HID_C];
    __shared__ float s_p[HID_C];
    __shared__ float s_t[HID_C];
    s_sum[half][f] = sum;
    __syncthreads();

    if (threadIdx.x < HID_C) {
        const float cnt = (float)(end - start);
        s_p[f] = (s_sum[0][f] + s_sum[1][f]) / fmaxf(cnt, 1.f);
    }
    __syncthreads();

    if (threadIdx.x < HID_C) {
        float acc = b1[f];
        for (int k = 0; k < HID_C; ++k) acc = fmaf(s_p[k], w1[k * HID_C + f], acc);
        s_t[f] = fmaxf(acc, 0.f);
    }
    __syncthreads();

    if (threadIdx.x < HID_C) {
        float acc = b2[f];
        for (int k = 0; k < HID_C; ++k) acc = fmaf(s_t[k], w2[k * HID_C + f], acc);
        out[(size_t)gid * HID_C + f] = acc;
    }
}

// ---------------------------------------------------------------------------
extern "C" void kernel_launch(void* const* d_in, const int* in_sizes, int n_in,
                              void* d_out, int out_size, void* d_ws, size_t ws_size,
                              hipStream_t stream)
{
    const float* x         = (const float*)d_in[0];
    const float* edge_attr = (const float*)d_in[1];
    const int*   edge_index= (const int*)  d_in[2];
    const int*   batch     = (const int*)  d_in[3];
    const int*   src = edge_index;
    const int*   dst = edge_index + N_EDGES_C;

    const float* el_w[3] = {(const float*)d_in[4],  (const float*)d_in[12], (const float*)d_in[20]};
    const float* el_b[3] = {(const float*)d_in[5],  (const float*)d_in[13], (const float*)d_in[21]};
    const float* c_w1[3] = {(const float*)d_in[6],  (const float*)d_in[14], (const float*)d_in[22]};
    const float* c_b1[3] = {(const float*)d_in[7],  (const float*)d_in[15], (const float*)d_in[23]};
    const float* c_g [3] = {(const float*)d_in[8],  (const float*)d_in[16], (const float*)d_in[24]};
    const float* c_bt[3] = {(const float*)d_in[9],  (const float*)d_in[17], (const float*)d_in[25]};
    const float* c_w2[3] = {(const float*)d_in[10], (const float*)d_in[18], (const float*)d_in[26]};
    const float* c_b2[3] = {(const float*)d_in[11], (const float*)d_in[19], (const float*)d_in[27]};
    const float* o_w1 = (const float*)d_in[28];
    const float* o_b1 = (const float*)d_in[29];
    const float* o_w2 = (const float*)d_in[30];
    const float* o_b2 = (const float*)d_in[31];

    // ---- workspace layout (~150 MB) ----
    char* wsp = (char*)d_ws;
    size_t used = 0;
    auto alloc = [&](size_t bytes) { char* p = wsp + used; used += (bytes + 255) & ~(size_t)255; return p; };
    int*   counts   = (int*)alloc((size_t)N_NODES_C * 4);
    int*   incl     = (int*)alloc((size_t)N_NODES_C * 4);
    int*   rowstart = (int*)alloc((size_t)N_NODES_C * 4);
    int*   cursor   = (int*)alloc((size_t)N_NODES_C * 4);
    int*   blocksums= (int*)alloc(128 * 4);
    int*   perm_src = (int*)alloc((size_t)N_EDGES_C * 4);
    _Float16* ea_f16 = (_Float16*)alloc((size_t)N_EDGES_C * 16 * 2);
    _Float16* x16    = (_Float16*)alloc((size_t)N_NODES_C * HID_C * 2);
    _Float16* h16_a  = (_Float16*)alloc((size_t)N_NODES_C * HID_C * 2);
    _Float16* h16_b  = (_Float16*)alloc((size_t)N_NODES_C * HID_C * 2);
    _Float16* x_f16  = (_Float16*)alloc((size_t)N_NODES_C * 64 * 2);
    _Float16* w1t[3], *w2t[3];
    for (int l = 0; l < 3; ++l) {
        w1t[l] = (_Float16*)alloc((size_t)HID_C * HID_C * 2);
        w2t[l] = (_Float16*)alloc((size_t)HID_C * HID_C * 2);
    }
    (void)ws_size;

    // ---- CSR build (once per launch; reused by all 3 layers) ----
    hipMemsetAsync(counts, 0, (size_t)N_NODES_C * 4, stream);
    hist_kernel<<<(N_EDGES_C + 255) / 256, 256, 0, stream>>>(dst, counts, N_EDGES_C);
    scan1_kernel<<<SCAN_NB, SCAN_B, 0, stream>>>(counts, incl, blocksums, N_NODES_C);
    scan3_kernel<<<SCAN_NB, SCAN_B, 0, stream>>>(incl, blocksums, N_NODES_C);
    initrows_kernel<<<(N_NODES_C + 255) / 256, 256, 0, stream>>>(incl, counts, rowstart,
                                                                 cursor, N_NODES_C);
    scatter_ea_kernel<<<(N_EDGES_C + 255) / 256, 256, 0, stream>>>(
        src, dst, cursor, perm_src, edge_attr, (__half*)ea_f16, N_EDGES_C);
    cast_f16_kernel<<<(N_NODES_C * 64 / 4 + 255) / 256, 256, 0, stream>>>(
        x, x_f16, N_NODES_C * 64 / 4);

    // fused weight transposes (6 segments, 1 launch)
    {
        WSeg s[6];
        int base = 0;
        for (int l = 0; l < 3; ++l) {
            const int K1 = (l == 0) ? 64 : HID_C;
            s[2 * l]     = { c_w1[l], w1t[l], K1,    HID_C, base }; base += K1 * HID_C;
            s[2 * l + 1] = { c_w2[l], w2t[l], HID_C, HID_C, base }; base += HID_C * HID_C;
        }
        transpose_all_kernel<<<(base + 255) / 256, 256, 0, stream>>>(
            s[0], s[1], s[2], s[3], s[4], s[5], base);
    }

    const int n_tiles = N_NODES_C / 16;            // 6250

    // ---- 3 GINE layers (split: high-TLP agg -> tiny MFMA node MLP) ----
    // layer 0 (DIN=64)
    gine_agg_kernel<64><<<(N_NODES_C + 15) / 16, 256, 0, stream>>>(
        x_f16, ea_f16, perm_src, rowstart, incl, el_w[0], el_b[0],
        x16, N_NODES_C);
    node_mfma_kernel<64><<<n_tiles, 64, 0, stream>>>(
        x16, w1t[0], c_b1[0], c_g[0], c_bt[0], w2t[0], c_b2[0],
        h16_a, n_tiles);
    // layer 1
    gine_agg_kernel<128><<<(N_NODES_C + 7) / 8, 256, 0, stream>>>(
        h16_a, ea_f16, perm_src, rowstart, incl, el_w[1], el_b[1],
        x16, N_NODES_C);
    node_mfma_kernel<128><<<n_tiles, 64, 0, stream>>>(
        x16, w1t[1], c_b1[1], c_g[1], c_bt[1], w2t[1], c_b2[1],
        h16_b, n_tiles);
    // layer 2
    gine_agg_kernel<128><<<(N_NODES_C + 7) / 8, 256, 0, stream>>>(
        h16_b, ea_f16, perm_src, rowstart, incl, el_w[2], el_b[2],
        x16, N_NODES_C);
    node_mfma_kernel<128><<<n_tiles, 64, 0, stream>>>(
        x16, w1t[2], c_b1[2], c_g[2], c_bt[2], w2t[2], c_b2[2],
        h16_a, n_tiles);

    // ---- pool + output MLP (reads f16) ----
    pool_kernel<<<N_GRAPHS_C, 256, 0, stream>>>(h16_a, batch, o_w1, o_b1, o_w2, o_b2,
                                                (float*)d_out, N_NODES_C);
}